// Round 8
// baseline (521.644 us; speedup 1.0000x reference)
//
#include <hip/hip_runtime.h>
#include <hip/hip_bf16.h>

// Problem constants (match reference setup_inputs)
static constexpr int N = 100000;
static constexpr int E = 600000;
static constexpr int D = 128;
static constexpr int B = 10000;
static constexpr int C = 32;
static constexpr int NB = (N + 1023) / 1024;               // 98 scan chunks
static constexpr int TOUCHB = (N * (D / 4) + 255) / 256;   // 12500 touch/zero blocks

typedef __attribute__((ext_vector_type(8))) short short8;   // 8 bf16 (4 VGPRs)
typedef __attribute__((ext_vector_type(4))) float f32x4;    // MFMA acc

// bf16 RNE helpers (bit-level, no NaN inputs here)
static __device__ __forceinline__ unsigned short f2bf(float f) {
    unsigned u = __float_as_uint(f);
    unsigned r = (u + 0x7FFFu + ((u >> 16) & 1u)) >> 16;
    return (unsigned short)r;
}
static __device__ __forceinline__ float bf2f(unsigned short h) {
    return __uint_as_float(((unsigned)h) << 16);
}

// split 8 consecutive floats into hi/lo bf16 fragments
static __device__ __forceinline__ void split8(const float4 v0, const float4 v1,
                                              short8& h, short8& l) {
    const float f[8] = {v0.x, v0.y, v0.z, v0.w, v1.x, v1.y, v1.z, v1.w};
    #pragma unroll
    for (int i = 0; i < 8; ++i) {
        unsigned short hh = f2bf(f[i]);
        h[i] = (short)hh;
        l[i] = (short)f2bf(f[i] - bf2f(hh));
    }
}

// ---------------- label marking (+ label rank for agg2 indexing) ----------------
// Duplicate label nodes: labrank[v] gets an arbitrary winner i; all rows of node v
// read agg2[labrank[v]] -> consistent.
__global__ void lab_k(const int* __restrict__ label_pos, int* __restrict__ labflag,
                      int* __restrict__ flag, int* __restrict__ labrank, int nlab) {
    int i = blockIdx.x * blockDim.x + threadIdx.x;
    if (i < nlab) {
        int v = label_pos[i];
        labflag[v] = 1;
        flag[v] = 1;       // labels are in U
        labrank[v] = i;    // benign race among duplicates
    }
}

// ---------------- pass 1: edge pass (deg + U-mark) + weight swizzle + touch/zero ----------------
// blocks [0, EB): per-edge deg atomic + flag[src]=1 where dst is a label.
// blocks [EB, EB+80): swizzle fp32 W[128][128] -> MFMA-B fragment order, hi/lo bf16.
// block  EB+80: swizzle Wc2 (128x32).
// blocks [EB+81, ...): stream node_state into L3 AND zero agg1 (same float4 index).
__global__ __launch_bounds__(256) void pass1_k(
    const int* __restrict__ src, const int* __restrict__ dst,
    const int* __restrict__ labflag,
    int* __restrict__ deg, int* __restrict__ flag, int nE, int EB,
    const float* W0, const float* W1, const float* W2, const float* W3,
    const float* W4, const float* W5,
    unsigned short* __restrict__ out,
    const float* __restrict__ xtouch, float* __restrict__ agg1,
    float* __restrict__ sink) {
    if ((int)blockIdx.x < EB) {
        int e = blockIdx.x * 256 + threadIdx.x;
        if (e < nE) {
            int d = dst[e];
            atomicAdd(&deg[d], 1);
            if (labflag[d]) flag[src[e]] = 1;   // benign race, all write 1
        }
        return;
    }
    if ((int)blockIdx.x < EB + 80) {
        const int sb = blockIdx.x - EB;          // 0..79
        const int m = sb >> 4;                   // 0..4
        const int chunk = sb & 15;
        const float* W = (m == 0) ? W0 : (m == 1) ? W1 : (m == 2) ? W2
                       : (m == 3) ? W3 : W4;
        unsigned short* o = out + (size_t)m * 32768;
        #pragma unroll
        for (int it = 0; it < 4; ++it) {
            int f = chunk * 1024 + it * 256 + threadIdx.x;   // 0..16383
            int j = f & 7;
            int lane = (f >> 3) & 63;
            int fi = f >> 9;                                 // ko*8+no
            int k = (fi >> 3) * 32 + (lane >> 4) * 8 + j;
            int n = (fi & 7) * 16 + (lane & 15);
            float a = W[k * 128 + n];
            unsigned short h = f2bf(a);
            o[f] = h;
            o[16384 + f] = f2bf(a - bf2f(h));
        }
        return;
    }
    if ((int)blockIdx.x == EB + 80) {
        unsigned short* o2 = out + (size_t)5 * 32768;
        #pragma unroll
        for (int it = 0; it < 16; ++it) {
            int f = it * 256 + threadIdx.x;   // 0..4095
            int j = f & 7;
            int lane = (f >> 3) & 63;
            int fi = f >> 9;                  // 0..7 = kp*2+no2
            int k = (fi >> 1) * 32 + (lane >> 4) * 8 + j;
            int n = (fi & 1) * 16 + (lane & 15);
            float a = W5[k * 32 + n];
            unsigned short h = f2bf(a);
            o2[f] = h;
            o2[4096 + f] = f2bf(a - bf2f(h));
        }
        return;
    }
    // ---- L3 warm touch of node_state + zero agg1 (same float4 index space)
    const int f4 = (blockIdx.x - (EB + 81)) * 256 + threadIdx.x;
    if (f4 < N * (D / 4)) {
        float4 v = reinterpret_cast<const float4*>(xtouch)[f4];
        reinterpret_cast<float4*>(agg1)[f4] = make_float4(0.f, 0.f, 0.f, 0.f);
        float s = v.x + v.y + v.z + v.w;
        if (s > 1e30f) *sink = s;   // data-dependent, never taken: keeps the loads
    }
}

// ---------------- flag-only compaction scans (sorted ulist/map; no deg scan needed) ----------------
__global__ __launch_bounds__(256) void scan1f_k(const int* __restrict__ flag,
                                                int* __restrict__ bsum, int n) {
    __shared__ int lsum[256];
    const int t = threadIdx.x;
    const int base = blockIdx.x * 1024 + t * 4;
    int s = 0;
    #pragma unroll
    for (int i = 0; i < 4; ++i) {
        int idx = base + i;
        if (idx < n) s += flag[idx];
    }
    lsum[t] = s;
    __syncthreads();
    for (int off = 128; off > 0; off >>= 1) {
        if (t < off) lsum[t] += lsum[t + off];
        __syncthreads();
    }
    if (t == 0) bsum[blockIdx.x] = lsum[0];
}

__global__ __launch_bounds__(256) void scan3f_k(
    const int* __restrict__ flag, const int* __restrict__ bsum,
    int* __restrict__ map, int* __restrict__ ulist, int* __restrict__ ucnt, int n)
{
    __shared__ int sb[128];
    __shared__ int lsum[256];
    const int t = threadIdx.x;

    if (t < 128) sb[t] = (t < NB) ? bsum[t] : 0;
    __syncthreads();
    for (int off = 1; off < 128; off <<= 1) {
        int u = (t < 128 && t >= off) ? sb[t - off] : 0;
        __syncthreads();
        if (t < 128) sb[t] += u;
        __syncthreads();
    }
    const int boff = (blockIdx.x == 0) ? 0 : sb[blockIdx.x - 1];
    if (blockIdx.x == 0 && t == 0) *ucnt = sb[NB - 1];

    const int base = blockIdx.x * 1024 + t * 4;
    int d[4];
    int s = 0;
    #pragma unroll
    for (int i = 0; i < 4; ++i) {
        int idx = base + i;
        d[i] = (idx < n) ? flag[idx] : 0;
        s += d[i];
    }
    lsum[t] = s;
    __syncthreads();
    for (int off = 1; off < 256; off <<= 1) {
        int u = (t >= off) ? lsum[t - off] : 0;
        __syncthreads();
        lsum[t] += u;
        __syncthreads();
    }
    int run = boff + lsum[t] - s;
    #pragma unroll
    for (int i = 0; i < 4; ++i) {
        int idx = base + i;
        if (idx < n && d[i]) {
            map[idx] = run;
            ulist[run] = idx;
            ++run;
        }
    }
}

// ---------------- scatter-aggregate layer 1: one wave per edge ----------------
// Replaces fill_k + gather_mean_k<1>: edge-parallel, no CSR, no degree imbalance.
// agg1 indexed by NODE id (zeroed in pass1). 294k flagged edges -> 37.6M f32 atomics.
__global__ __launch_bounds__(256) void scatter1_k(
    const int* __restrict__ src, const int* __restrict__ dst,
    const int* __restrict__ flag,
    const float* __restrict__ x, float* __restrict__ agg1, int nE)
{
    const int w = blockIdx.x * 4 + (threadIdx.x >> 6);
    if (w >= nE) return;
    const int d = dst[w];
    if (!flag[d]) return;                 // wave-uniform
    const int s = src[w];
    const int lane = threadIdx.x & 63;
    float2 v = *reinterpret_cast<const float2*>(x + (size_t)s * D + lane * 2);
    float* a = agg1 + (size_t)d * D + lane * 2;
    atomicAdd(a, v.x);
    atomicAdd(a + 1, v.y);
}

// ---------------- scatter-aggregate layer 2: one wave per label-destined edge ----------------
// agg2 indexed by labrank[dst] (B x D, zeroed by memset). src is flagged by
// construction -> x1c[map[src]] valid.
__global__ __launch_bounds__(256) void scatter2_k(
    const int* __restrict__ src, const int* __restrict__ dst,
    const int* __restrict__ labflag, const int* __restrict__ labrank,
    const int* __restrict__ map,
    const float* __restrict__ x1c, float* __restrict__ agg2, int nE)
{
    const int w = blockIdx.x * 4 + (threadIdx.x >> 6);
    if (w >= nE) return;
    const int d = dst[w];
    if (!labflag[d]) return;              // wave-uniform; ~60k edges survive
    const int s = map[src[w]];
    const int lr = labrank[d];
    const int lane = threadIdx.x & 63;
    float2 v = *reinterpret_cast<const float2*>(x1c + (size_t)s * D + lane * 2);
    float* a = agg2 + (size_t)lr * D + lane * 2;
    atomicAdd(a, v.x);
    atomicAdd(a + 1, v.y);
}

// ---------------- SAGE layer 1, split-bf16 MFMA (mean = agg1/deg inline) ----------------
// 32-row blocks, 4 waves = {row-half} x {col-half}; each wave 16 rows x 64 cols.
__global__ __launch_bounds__(256, 6) void sage_mfma_k(
    const float* __restrict__ agg1, const int* __restrict__ deg,
    const float* __restrict__ xsrc, const int* __restrict__ ulist,
    const int* __restrict__ nrows_ptr,
    const unsigned short* __restrict__ WlSw, const unsigned short* __restrict__ WrSw,
    const float* __restrict__ bl, float* __restrict__ xout)
{
    const int nrows = nrows_ptr[0];
    const int rb = blockIdx.x * 32;
    if (rb >= nrows) return;

    const int t = threadIdx.x;
    const int wrow = (t >> 6) & 1;
    const int wcol = t >> 7;
    const int lane = t & 63;
    const int mcol = lane & 15;
    const int q = lane >> 4;
    const int r = rb + wrow * 16 + mcol;

    f32x4 acc[4];
    #pragma unroll
    for (int no = 0; no < 4; ++no) acc[no] = (f32x4){0.f, 0.f, 0.f, 0.f};

    size_t gidx = 0;
    float invd = 0.f;
    if (r < nrows) {
        int g = ulist[r];
        gidx = (size_t)g;
        invd = 1.0f / fmaxf((float)deg[g], 1.0f);
    }

    #pragma unroll
    for (int br = 0; br < 2; ++br) {
        const unsigned short* __restrict__ Wm = br ? WrSw : WlSw;
        #pragma unroll
        for (int kp = 0; kp < 4; ++kp) {
            short8 aH, aL;
            {
                float4 v0 = make_float4(0.f, 0.f, 0.f, 0.f);
                float4 v1 = make_float4(0.f, 0.f, 0.f, 0.f);
                if (r < nrows) {
                    const float* p = (br == 0)
                        ? agg1 + gidx * D + kp * 32 + q * 8
                        : xsrc + gidx * D + kp * 32 + q * 8;
                    v0 = *reinterpret_cast<const float4*>(p);
                    v1 = *reinterpret_cast<const float4*>(p + 4);
                    if (br == 0) {
                        v0.x *= invd; v0.y *= invd; v0.z *= invd; v0.w *= invd;
                        v1.x *= invd; v1.y *= invd; v1.z *= invd; v1.w *= invd;
                    }
                }
                split8(v0, v1, aH, aL);
            }
            #pragma unroll
            for (int no = 0; no < 4; ++no) {
                const size_t fo = ((size_t)(kp * 8 + wcol * 4 + no) * 64 + lane) * 8;
                short8 bh = *reinterpret_cast<const short8*>(Wm + fo);
                short8 bo = *reinterpret_cast<const short8*>(Wm + 16384 + fo);
                acc[no] = __builtin_amdgcn_mfma_f32_16x16x32_bf16(aH, bh, acc[no], 0, 0, 0);
                acc[no] = __builtin_amdgcn_mfma_f32_16x16x32_bf16(aL, bh, acc[no], 0, 0, 0);
                acc[no] = __builtin_amdgcn_mfma_f32_16x16x32_bf16(aH, bo, acc[no], 0, 0, 0);
            }
        }
    }

    #pragma unroll
    for (int no = 0; no < 4; ++no) {
        const int col = wcol * 64 + no * 16 + mcol;
        const float bias = bl[col];
        #pragma unroll
        for (int ri = 0; ri < 4; ++ri) {
            const int row = rb + wrow * 16 + q * 4 + ri;
            if (row < nrows)
                xout[(size_t)row * D + col] = fmaxf(acc[no][ri] + bias, 0.f);
        }
    }
}

// ---------------- fused layer-2 + classifier (mean2 = agg2/deg inline) ----------------
__global__ __launch_bounds__(256) void sage2_cls_k(
    const float* __restrict__ agg2, const int* __restrict__ deg,
    const float* __restrict__ x1c,
    const int* __restrict__ label_pos, const int* __restrict__ map,
    const int* __restrict__ labrank,
    const unsigned short* __restrict__ WlSw, const unsigned short* __restrict__ WrSw,
    const float* __restrict__ bl,
    const unsigned short* __restrict__ Wc1Sw, const float* __restrict__ bc1,
    const unsigned short* __restrict__ Wc2Sw, const float* __restrict__ bc2,
    float* __restrict__ out, int nrows)
{
    __shared__ alignas(16) float Xs[32][132];   // x2 tile (+4 pad)
    __shared__ alignas(16) float Hs[32][132];   // h tile
    const int rb = blockIdx.x * 32;
    const int t = threadIdx.x;
    const int wrow = (t >> 6) & 1;
    const int wcol = t >> 7;
    const int lane = t & 63;
    const int mcol = lane & 15;
    const int q = lane >> 4;
    const int r = rb + wrow * 16 + mcol;

    // ---- stage 1
    f32x4 acc[4];
    #pragma unroll
    for (int no = 0; no < 4; ++no) acc[no] = (f32x4){0.f, 0.f, 0.f, 0.f};

    size_t gidx = 0, aidx = 0;
    float invd = 0.f;
    if (r < nrows) {
        const int n = label_pos[r];
        gidx = (size_t)map[n];
        aidx = (size_t)labrank[n];
        invd = 1.0f / fmaxf((float)deg[n], 1.0f);
    }

    #pragma unroll
    for (int br = 0; br < 2; ++br) {
        const unsigned short* __restrict__ Wm = br ? WrSw : WlSw;
        #pragma unroll
        for (int kp = 0; kp < 4; ++kp) {
            short8 aH, aL;
            {
                float4 v0 = make_float4(0.f, 0.f, 0.f, 0.f);
                float4 v1 = make_float4(0.f, 0.f, 0.f, 0.f);
                if (r < nrows) {
                    const float* p = (br == 0)
                        ? agg2 + aidx * D + kp * 32 + q * 8
                        : x1c + gidx * D + kp * 32 + q * 8;
                    v0 = *reinterpret_cast<const float4*>(p);
                    v1 = *reinterpret_cast<const float4*>(p + 4);
                    if (br == 0) {
                        v0.x *= invd; v0.y *= invd; v0.z *= invd; v0.w *= invd;
                        v1.x *= invd; v1.y *= invd; v1.z *= invd; v1.w *= invd;
                    }
                }
                split8(v0, v1, aH, aL);
            }
            #pragma unroll
            for (int no = 0; no < 4; ++no) {
                const size_t fo = ((size_t)(kp * 8 + wcol * 4 + no) * 64 + lane) * 8;
                short8 bh = *reinterpret_cast<const short8*>(Wm + fo);
                short8 bo = *reinterpret_cast<const short8*>(Wm + 16384 + fo);
                acc[no] = __builtin_amdgcn_mfma_f32_16x16x32_bf16(aH, bh, acc[no], 0, 0, 0);
                acc[no] = __builtin_amdgcn_mfma_f32_16x16x32_bf16(aL, bh, acc[no], 0, 0, 0);
                acc[no] = __builtin_amdgcn_mfma_f32_16x16x32_bf16(aH, bo, acc[no], 0, 0, 0);
            }
        }
    }

    // epilogue -> LDS tile (unconditional: junk rows masked at final store)
    #pragma unroll
    for (int no = 0; no < 4; ++no) {
        const int col = wcol * 64 + no * 16 + mcol;
        const float bias = bl[col];
        #pragma unroll
        for (int ri = 0; ri < 4; ++ri) {
            const int lrow = wrow * 16 + q * 4 + ri;
            Xs[lrow][col] = fmaxf(acc[no][ri] + bias, 0.f);
        }
    }
    __syncthreads();

    // ---- stage 2: h = relu(x2 @ Wc1 + bc1)
    {
        f32x4 acc2[4];
        #pragma unroll
        for (int no = 0; no < 4; ++no) acc2[no] = (f32x4){0.f, 0.f, 0.f, 0.f};

        #pragma unroll
        for (int kp = 0; kp < 4; ++kp) {
            short8 aH, aL;
            {
                const float* p = &Xs[wrow * 16 + mcol][kp * 32 + q * 8];
                float4 v0 = *reinterpret_cast<const float4*>(p);
                float4 v1 = *reinterpret_cast<const float4*>(p + 4);
                split8(v0, v1, aH, aL);
            }
            #pragma unroll
            for (int no = 0; no < 4; ++no) {
                const size_t fo = ((size_t)(kp * 8 + wcol * 4 + no) * 64 + lane) * 8;
                short8 bh = *reinterpret_cast<const short8*>(Wc1Sw + fo);
                short8 bo = *reinterpret_cast<const short8*>(Wc1Sw + 16384 + fo);
                acc2[no] = __builtin_amdgcn_mfma_f32_16x16x32_bf16(aH, bh, acc2[no], 0, 0, 0);
                acc2[no] = __builtin_amdgcn_mfma_f32_16x16x32_bf16(aL, bh, acc2[no], 0, 0, 0);
                acc2[no] = __builtin_amdgcn_mfma_f32_16x16x32_bf16(aH, bo, acc2[no], 0, 0, 0);
            }
        }
        #pragma unroll
        for (int no = 0; no < 4; ++no) {
            const int col = wcol * 64 + no * 16 + mcol;
            const float bias = bc1[col];
            #pragma unroll
            for (int ri = 0; ri < 4; ++ri) {
                const int lrow = wrow * 16 + q * 4 + ri;
                Hs[lrow][col] = fmaxf(acc2[no][ri] + bias, 0.0f);
            }
        }
    }
    __syncthreads();

    // ---- stage 3: out = h @ Wc2 + bc2 (wave = one 16x16 tile)
    {
        f32x4 acc3 = (f32x4){0.f, 0.f, 0.f, 0.f};
        #pragma unroll
        for (int kp = 0; kp < 4; ++kp) {
            short8 aH, aL;
            {
                const float* p = &Hs[wrow * 16 + mcol][kp * 32 + q * 8];
                float4 v0 = *reinterpret_cast<const float4*>(p);
                float4 v1 = *reinterpret_cast<const float4*>(p + 4);
                split8(v0, v1, aH, aL);
            }
            const size_t fo = ((size_t)(kp * 2 + wcol) * 64 + lane) * 8;
            short8 bh = *reinterpret_cast<const short8*>(Wc2Sw + fo);
            short8 bo = *reinterpret_cast<const short8*>(Wc2Sw + 4096 + fo);
            acc3 = __builtin_amdgcn_mfma_f32_16x16x32_bf16(aH, bh, acc3, 0, 0, 0);
            acc3 = __builtin_amdgcn_mfma_f32_16x16x32_bf16(aL, bh, acc3, 0, 0, 0);
            acc3 = __builtin_amdgcn_mfma_f32_16x16x32_bf16(aH, bo, acc3, 0, 0, 0);
        }
        const int col = wcol * 16 + mcol;
        const float b2 = bc2[col];
        #pragma unroll
        for (int ri = 0; ri < 4; ++ri) {
            const int row = rb + wrow * 16 + q * 4 + ri;
            if (row < nrows) out[(size_t)row * C + col] = acc3[ri] + b2;
        }
    }
}

// ---------------- launch ----------------

extern "C" void kernel_launch(void* const* d_in, const int* in_sizes, int n_in,
                              void* d_out, int out_size, void* d_ws, size_t ws_size,
                              hipStream_t stream) {
    const float* node_state = (const float*)d_in[0];
    const int*   edge_index = (const int*)d_in[1];
    const int*   label_pos  = (const int*)d_in[2];
    const float* W1l = (const float*)d_in[3];
    const float* b1l = (const float*)d_in[4];
    const float* W1r = (const float*)d_in[5];
    const float* W2l = (const float*)d_in[6];
    const float* b2l = (const float*)d_in[7];
    const float* W2r = (const float*)d_in[8];
    const float* Wc1 = (const float*)d_in[9];
    const float* bc1 = (const float*)d_in[10];
    const float* Wc2 = (const float*)d_in[11];
    const float* bc2 = (const float*)d_in[12];
    float* out = (float*)d_out;

    const int* src = edge_index;       // edge_index[0]
    const int* dst = edge_index + E;   // edge_index[1]

    // workspace layout (floats first for alignment)
    char* ws = (char*)d_ws;
    float* x1c   = (float*)ws;                    ws += sizeof(float) * (size_t)N * D;
    float* agg1  = (float*)ws;                    ws += sizeof(float) * (size_t)N * D;
    float* agg2  = (float*)ws;                    ws += sizeof(float) * (size_t)B * D;
    unsigned short* Wsw = (unsigned short*)ws;    ws += sizeof(unsigned short) * (5 * 32768 + 8192);
    int* deg     = (int*)ws;                      ws += sizeof(int) * N;   // |
    int* flag    = (int*)ws;                      ws += sizeof(int) * N;   // | contiguous: one
    int* labflag = (int*)ws;                      ws += sizeof(int) * N;   // | memset
    int* ucnt    = (int*)ws;                      ws += sizeof(int);       // |
    float* sink  = (float*)ws;                    ws += sizeof(float);
    ws += sizeof(int) * 2;                        // pad to 16B
    int* labrank = (int*)ws;                      ws += sizeof(int) * N;
    int* map     = (int*)ws;                      ws += sizeof(int) * N;
    int* ulist   = (int*)ws;                      ws += sizeof(int) * N;
    int* bsum    = (int*)ws;                      ws += sizeof(int) * 128;

    const int TB = 256;
    const int EB = (E + TB - 1) / TB;   // 2344 edge blocks
    const int SB = (E + 3) / 4;         // 150000 scatter blocks (4 waves/block, 1 edge/wave)

    // ---- preprocessing ----
    hipMemsetAsync(deg, 0, sizeof(int) * (3 * N + 1), stream);     // deg,flag,labflag,ucnt
    hipMemsetAsync(agg2, 0, sizeof(float) * (size_t)B * D, stream); // layer-2 accumulator
    lab_k<<<(B + TB - 1) / TB, TB, 0, stream>>>(label_pos, labflag, flag, labrank, B);
    pass1_k<<<EB + 81 + TOUCHB, TB, 0, stream>>>(src, dst, labflag, deg, flag, E, EB,
                                                 W1l, W1r, W2l, W2r, Wc1, Wc2, Wsw,
                                                 node_state, agg1, sink);
    scan1f_k<<<NB, 256, 0, stream>>>(flag, bsum, N);
    scan3f_k<<<NB, 256, 0, stream>>>(flag, bsum, map, ulist, ucnt, N);

    // ---- layer 1: scatter-aggregate then MFMA over compact U rows ----
    scatter1_k<<<SB, TB, 0, stream>>>(src, dst, flag, node_state, agg1, E);
    sage_mfma_k<<<(N + 31) / 32, TB, 0, stream>>>(
        agg1, deg, node_state, ulist, ucnt,
        Wsw, Wsw + 32768, b1l, x1c);

    // ---- layer 2 + classifier: scatter-aggregate then fused 3-stage MFMA ----
    scatter2_k<<<SB, TB, 0, stream>>>(src, dst, labflag, labrank, map, x1c, agg2, E);
    sage2_cls_k<<<(B + 31) / 32, TB, 0, stream>>>(
        agg2, deg, x1c, label_pos, map, labrank,
        Wsw + 65536, Wsw + 98304, b2l,
        Wsw + 131072, bc1,
        Wsw + 163840, bc2, out, B);
}

// Round 10
// 275.351 us; speedup vs baseline: 1.8945x; 1.8945x over previous
//
#include <hip/hip_runtime.h>
#include <hip/hip_bf16.h>

// Problem constants (match reference setup_inputs)
static constexpr int N = 100000;
static constexpr int E = 600000;
static constexpr int D = 128;
static constexpr int B = 10000;
static constexpr int C = 32;
static constexpr int NB = (N + 1023) / 1024;   // 98 scan chunks per N-array
static constexpr int TOUCHB = (N * (D / 4) + 255) / 256;   // 12500 float4-touch blocks

typedef __attribute__((ext_vector_type(8))) short short8;   // 8 bf16 (4 VGPRs)
typedef __attribute__((ext_vector_type(4))) float f32x4;    // MFMA acc

// bf16 RNE helpers (bit-level, no NaN inputs here)
static __device__ __forceinline__ unsigned short f2bf(float f) {
    unsigned u = __float_as_uint(f);
    unsigned r = (u + 0x7FFFu + ((u >> 16) & 1u)) >> 16;
    return (unsigned short)r;
}
static __device__ __forceinline__ float bf2f(unsigned short h) {
    return __uint_as_float(((unsigned)h) << 16);
}

// split 8 consecutive floats into hi/lo bf16 fragments
static __device__ __forceinline__ void split8(const float4 v0, const float4 v1,
                                              short8& h, short8& l) {
    const float f[8] = {v0.x, v0.y, v0.z, v0.w, v1.x, v1.y, v1.z, v1.w};
    #pragma unroll
    for (int i = 0; i < 8; ++i) {
        unsigned short hh = f2bf(f[i]);
        h[i] = (short)hh;
        l[i] = (short)f2bf(f[i] - bf2f(hh));
    }
}

// ---------------- label marking ----------------
__global__ void lab_k(const int* __restrict__ label_pos, int* __restrict__ labflag,
                      int* __restrict__ flag, int nlab) {
    int i = blockIdx.x * blockDim.x + threadIdx.x;
    if (i < nlab) {
        int v = label_pos[i];
        labflag[v] = 1;
        flag[v] = 1;   // labels are in U
    }
}

// ---------------- merged edge pass (deg + U-mark) + weight swizzle + L3 touch ----------------
// (verbatim R5 structure)
__global__ __launch_bounds__(256) void deg_swz_k(
    const int* __restrict__ src, const int* __restrict__ dst,
    const int* __restrict__ labflag,
    int* __restrict__ deg, int* __restrict__ flag, int nE, int EB,
    const float* W0, const float* W1, const float* W2, const float* W3,
    const float* W4, const float* W5,
    unsigned short* __restrict__ out,
    const float* __restrict__ xtouch, float* __restrict__ sink) {
    if ((int)blockIdx.x < EB) {
        int e = blockIdx.x * 256 + threadIdx.x;
        if (e < nE) {
            int d = dst[e];
            atomicAdd(&deg[d], 1);
            if (labflag[d]) flag[src[e]] = 1;   // benign race, all write 1
        }
        return;
    }
    if ((int)blockIdx.x < EB + 80) {
        const int sb = blockIdx.x - EB;          // 0..79
        const int m = sb >> 4;                   // 0..4
        const int chunk = sb & 15;
        const float* W = (m == 0) ? W0 : (m == 1) ? W1 : (m == 2) ? W2
                       : (m == 3) ? W3 : W4;
        unsigned short* o = out + (size_t)m * 32768;
        #pragma unroll
        for (int it = 0; it < 4; ++it) {
            int f = chunk * 1024 + it * 256 + threadIdx.x;   // 0..16383
            int j = f & 7;
            int lane = (f >> 3) & 63;
            int fi = f >> 9;                                 // ko*8+no
            int k = (fi >> 3) * 32 + (lane >> 4) * 8 + j;
            int n = (fi & 7) * 16 + (lane & 15);
            float a = W[k * 128 + n];
            unsigned short h = f2bf(a);
            o[f] = h;
            o[16384 + f] = f2bf(a - bf2f(h));
        }
        return;
    }
    if ((int)blockIdx.x == EB + 80) {
        unsigned short* o2 = out + (size_t)5 * 32768;
        #pragma unroll
        for (int it = 0; it < 16; ++it) {
            int f = it * 256 + threadIdx.x;   // 0..4095
            int j = f & 7;
            int lane = (f >> 3) & 63;
            int fi = f >> 9;                  // 0..7 = kp*2+no2
            int k = (fi >> 1) * 32 + (lane >> 4) * 8 + j;
            int n = (fi & 1) * 16 + (lane & 15);
            float a = W5[k * 32 + n];
            unsigned short h = f2bf(a);
            o2[f] = h;
            o2[4096 + f] = f2bf(a - bf2f(h));
        }
        return;
    }
    // ---- L3 warm touch of node_state
    const int f4 = (blockIdx.x - (EB + 81)) * 256 + threadIdx.x;
    if (f4 < N * (D / 4)) {
        float4 v = reinterpret_cast<const float4*>(xtouch)[f4];
        float s = v.x + v.y + v.z + v.w;
        if (s > 1e30f) *sink = s;   // data-dependent, never taken: keeps the loads
    }
}

// ---------------- merged scan + fill: ONE kernel, 2*NB=196 blocks ----------------
// 196 blocks <= 256 CUs => guaranteed co-resident => software global barrier is safe
// (device-scope atomics; sync4[4] = {ctr1,done1,ctr2,done2} zeroed by the memset).
// Phase A: per-chunk sums + intra-block scan (deg group / flag group), registers kept.
// Barrier 1. Each block then SELF-computes its group prefix from bsum (98-wide
// parallel reduction, no serial scan, no boff array). Phase B: apply (roff/cur or
// map/ulist) from registers. Barrier 2. Phase C: grid-stride gated CSR fill.
__global__ __launch_bounds__(256) void prep_k(
    const int* __restrict__ deg, const int* __restrict__ flag,
    const int* __restrict__ src, const int* __restrict__ dst,
    int* __restrict__ bsum,
    int* __restrict__ roff, int* __restrict__ cur,
    int* __restrict__ map, int* __restrict__ ulist, int* __restrict__ ucnt,
    int* __restrict__ csr_src, int* __restrict__ sync4, int nE, int EBv)
{
    __shared__ int lsum[256];
    __shared__ int s_blk;
    const int t = threadIdx.x;
    const bool isdeg = (int)blockIdx.x < NB;
    const int bloc = isdeg ? blockIdx.x : blockIdx.x - NB;
    const int gbase = isdeg ? 0 : NB;
    const int* v = isdeg ? deg : flag;

    // ---- phase A: chunk load + intra-block inclusive scan
    const int base = bloc * 1024 + t * 4;
    int dd[4];
    int s = 0;
    #pragma unroll
    for (int i = 0; i < 4; ++i) {
        int idx = base + i;
        dd[i] = (idx < N) ? v[idx] : 0;
        s += dd[i];
    }
    lsum[t] = s;
    __syncthreads();
    for (int off = 1; off < 256; off <<= 1) {
        int u = (t >= off) ? lsum[t - off] : 0;
        __syncthreads();
        lsum[t] += u;
        __syncthreads();
    }
    const int tpre = lsum[t] - s;           // exclusive prefix within block
    if (t == 255) s_blk = lsum[255];        // block total
    if (t == 0) bsum[blockIdx.x] = lsum[255];
    __syncthreads();
    const int sblk = s_blk;

    // ---- global barrier 1
    __threadfence();
    __syncthreads();
    if (t == 0) {
        int old = atomicAdd(&sync4[0], 1);
        if (old == 2 * NB - 1) atomicExch(&sync4[1], 1);
        while (atomicAdd(&sync4[1], 0) == 0) {}
    }
    __syncthreads();

    // ---- self-service group prefix: boff = sum of bsum[gbase .. gbase+bloc-1]
    int pv = 0;
    if (t < bloc) pv = atomicAdd(&bsum[gbase + t], 0);   // coherent read
    lsum[t] = pv;
    __syncthreads();
    for (int off = 128; off > 0; off >>= 1) {
        if (t < off) lsum[t] += lsum[t + off];
        __syncthreads();
    }
    const int boffv = lsum[0];
    if (bloc == NB - 1 && t == 0) {
        if (isdeg) roff[N] = boffv + sblk;   // == E (gated total)
        else *ucnt = boffv + sblk;
    }

    // ---- phase B: apply (registers dd/tpre survive the barrier)
    int run = boffv + tpre;
    #pragma unroll
    for (int i = 0; i < 4; ++i) {
        int idx = base + i;
        if (idx < N) {
            if (isdeg) {
                roff[idx] = run;
                cur[idx]  = run;
                run += dd[i];
            } else if (dd[i]) {
                map[idx] = run;
                ulist[run] = idx;
                ++run;
            }
        }
    }

    // ---- global barrier 2 (all roff/cur visible before fill)
    __threadfence();
    __syncthreads();
    if (t == 0) {
        int old = atomicAdd(&sync4[2], 1);
        if (old == 2 * NB - 1) atomicExch(&sync4[3], 1);
        while (atomicAdd(&sync4[3], 0) == 0) {}
    }
    __syncthreads();

    // ---- phase C: gated CSR fill, grid-strided over edge vblocks
    for (int vb = blockIdx.x; vb < EBv; vb += 2 * NB) {
        int e = vb * 256 + t;
        if (e < nE) {
            int d = dst[e];
            if (flag[d]) {
                int p = atomicAdd(&cur[d], 1);
                csr_src[p] = src[e];
            }
        }
    }
}

// ---------------- gather-mean aggregation (verbatim R5) ----------------
template <bool GATHER, bool MAP>
__global__ __launch_bounds__(256) void gather_mean_k(
    const float* __restrict__ x, const int* __restrict__ roff,
    const int* __restrict__ csr_src, const int* __restrict__ rows,
    const int* __restrict__ map, const int* __restrict__ nrows_ptr,
    float* __restrict__ out, int nrows_max) {
    const int nrows = nrows_ptr ? nrows_ptr[0] : nrows_max;
    const int w = blockIdx.x * (blockDim.x >> 6) + (threadIdx.x >> 6);
    if (w >= nrows) return;
    const int lane = threadIdx.x & 63;
    const int n  = GATHER ? rows[w] : w;
    const int jb = roff[n];
    const int je = roff[n + 1];
    const float* xb = x + lane * 2;

    float ax = 0.f, ay = 0.f;
    int j = jb;
    for (; j + 4 <= je; j += 4) {
        int s0 = csr_src[j + 0];
        int s1 = csr_src[j + 1];
        int s2 = csr_src[j + 2];
        int s3 = csr_src[j + 3];
        if (MAP) { s0 = map[s0]; s1 = map[s1]; s2 = map[s2]; s3 = map[s3]; }
        float2 v0 = *reinterpret_cast<const float2*>(xb + (size_t)s0 * D);
        float2 v1 = *reinterpret_cast<const float2*>(xb + (size_t)s1 * D);
        float2 v2 = *reinterpret_cast<const float2*>(xb + (size_t)s2 * D);
        float2 v3 = *reinterpret_cast<const float2*>(xb + (size_t)s3 * D);
        ax += v0.x + v1.x + v2.x + v3.x;
        ay += v0.y + v1.y + v2.y + v3.y;
    }
    for (; j < je; ++j) {
        int s = csr_src[j];
        if (MAP) s = map[s];
        float2 v = *reinterpret_cast<const float2*>(xb + (size_t)s * D);
        ax += v.x;
        ay += v.y;
    }
    const float inv = 1.0f / fmaxf((float)(je - jb), 1.0f);
    *reinterpret_cast<float2*>(out + (size_t)w * D + lane * 2) =
        make_float2(ax * inv, ay * inv);
}

// ---------------- SAGE layer 1, split-bf16 MFMA (verbatim R5) ----------------
template <bool GATHER, bool MAP>
__global__ __launch_bounds__(256, 6) void sage_mfma_k(
    const float* __restrict__ mean, const float* __restrict__ xsrc,
    const int* __restrict__ rows, const int* __restrict__ map,
    const int* __restrict__ nrows_ptr,
    const unsigned short* __restrict__ WlSw, const unsigned short* __restrict__ WrSw,
    const float* __restrict__ bl, float* __restrict__ xout, int nrows_max)
{
    const int nrows = nrows_ptr ? nrows_ptr[0] : nrows_max;
    const int rb = blockIdx.x * 32;
    if (rb >= nrows) return;

    const int t = threadIdx.x;
    const int wrow = (t >> 6) & 1;
    const int wcol = t >> 7;
    const int lane = t & 63;
    const int mcol = lane & 15;
    const int q = lane >> 4;
    const int r = rb + wrow * 16 + mcol;

    f32x4 acc[4];
    #pragma unroll
    for (int no = 0; no < 4; ++no) acc[no] = (f32x4){0.f, 0.f, 0.f, 0.f};

    size_t gidx = 0;
    if (r < nrows) {
        int g = GATHER ? rows[r] : r;
        if (MAP) g = map[g];
        gidx = (size_t)g;
    }

    #pragma unroll
    for (int br = 0; br < 2; ++br) {
        const unsigned short* __restrict__ Wm = br ? WrSw : WlSw;
        #pragma unroll
        for (int kp = 0; kp < 4; ++kp) {
            short8 aH, aL;
            {
                float4 v0 = make_float4(0.f, 0.f, 0.f, 0.f);
                float4 v1 = make_float4(0.f, 0.f, 0.f, 0.f);
                if (r < nrows) {
                    const float* p = (br == 0)
                        ? mean + (size_t)r * D + kp * 32 + q * 8
                        : xsrc + gidx * D + kp * 32 + q * 8;
                    v0 = *reinterpret_cast<const float4*>(p);
                    v1 = *reinterpret_cast<const float4*>(p + 4);
                }
                split8(v0, v1, aH, aL);
            }
            #pragma unroll
            for (int no = 0; no < 4; ++no) {
                const size_t fo = ((size_t)(kp * 8 + wcol * 4 + no) * 64 + lane) * 8;
                short8 bh = *reinterpret_cast<const short8*>(Wm + fo);
                short8 bo = *reinterpret_cast<const short8*>(Wm + 16384 + fo);
                acc[no] = __builtin_amdgcn_mfma_f32_16x16x32_bf16(aH, bh, acc[no], 0, 0, 0);
                acc[no] = __builtin_amdgcn_mfma_f32_16x16x32_bf16(aL, bh, acc[no], 0, 0, 0);
                acc[no] = __builtin_amdgcn_mfma_f32_16x16x32_bf16(aH, bo, acc[no], 0, 0, 0);
            }
        }
    }

    #pragma unroll
    for (int no = 0; no < 4; ++no) {
        const int col = wcol * 64 + no * 16 + mcol;
        const float bias = bl[col];
        #pragma unroll
        for (int ri = 0; ri < 4; ++ri) {
            const int row = rb + wrow * 16 + q * 4 + ri;
            if (row < nrows)
                xout[(size_t)row * D + col] = fmaxf(acc[no][ri] + bias, 0.f);
        }
    }
}

// ---------------- fused layer-2 + classifier (verbatim R5) ----------------
__global__ __launch_bounds__(256) void sage2_cls_k(
    const float* __restrict__ mean, const float* __restrict__ x1c,
    const int* __restrict__ label_pos, const int* __restrict__ map,
    const unsigned short* __restrict__ WlSw, const unsigned short* __restrict__ WrSw,
    const float* __restrict__ bl,
    const unsigned short* __restrict__ Wc1Sw, const float* __restrict__ bc1,
    const unsigned short* __restrict__ Wc2Sw, const float* __restrict__ bc2,
    float* __restrict__ out, int nrows)
{
    __shared__ alignas(16) float Xs[32][132];   // x2 tile (+4 pad)
    __shared__ alignas(16) float Hs[32][132];   // h tile (+4 pad: conflict-free A-reads)
    const int rb = blockIdx.x * 32;
    const int t = threadIdx.x;
    const int wrow = (t >> 6) & 1;
    const int wcol = t >> 7;
    const int lane = t & 63;
    const int mcol = lane & 15;
    const int q = lane >> 4;
    const int r = rb + wrow * 16 + mcol;

    // ---- stage 1
    f32x4 acc[4];
    #pragma unroll
    for (int no = 0; no < 4; ++no) acc[no] = (f32x4){0.f, 0.f, 0.f, 0.f};

    size_t gidx = 0;
    if (r < nrows) gidx = (size_t)map[label_pos[r]];

    #pragma unroll
    for (int br = 0; br < 2; ++br) {
        const unsigned short* __restrict__ Wm = br ? WrSw : WlSw;
        #pragma unroll
        for (int kp = 0; kp < 4; ++kp) {
            short8 aH, aL;
            {
                float4 v0 = make_float4(0.f, 0.f, 0.f, 0.f);
                float4 v1 = make_float4(0.f, 0.f, 0.f, 0.f);
                if (r < nrows) {
                    const float* p = (br == 0)
                        ? mean + (size_t)r * D + kp * 32 + q * 8
                        : x1c + gidx * D + kp * 32 + q * 8;
                    v0 = *reinterpret_cast<const float4*>(p);
                    v1 = *reinterpret_cast<const float4*>(p + 4);
                }
                split8(v0, v1, aH, aL);
            }
            #pragma unroll
            for (int no = 0; no < 4; ++no) {
                const size_t fo = ((size_t)(kp * 8 + wcol * 4 + no) * 64 + lane) * 8;
                short8 bh = *reinterpret_cast<const short8*>(Wm + fo);
                short8 bo = *reinterpret_cast<const short8*>(Wm + 16384 + fo);
                acc[no] = __builtin_amdgcn_mfma_f32_16x16x32_bf16(aH, bh, acc[no], 0, 0, 0);
                acc[no] = __builtin_amdgcn_mfma_f32_16x16x32_bf16(aL, bh, acc[no], 0, 0, 0);
                acc[no] = __builtin_amdgcn_mfma_f32_16x16x32_bf16(aH, bo, acc[no], 0, 0, 0);
            }
        }
    }

    #pragma unroll
    for (int no = 0; no < 4; ++no) {
        const int col = wcol * 64 + no * 16 + mcol;
        const float bias = bl[col];
        #pragma unroll
        for (int ri = 0; ri < 4; ++ri) {
            const int lrow = wrow * 16 + q * 4 + ri;
            Xs[lrow][col] = fmaxf(acc[no][ri] + bias, 0.f);
        }
    }
    __syncthreads();

    // ---- stage 2
    {
        f32x4 acc2[4];
        #pragma unroll
        for (int no = 0; no < 4; ++no) acc2[no] = (f32x4){0.f, 0.f, 0.f, 0.f};

        #pragma unroll
        for (int kp = 0; kp < 4; ++kp) {
            short8 aH, aL;
            {
                const float* p = &Xs[wrow * 16 + mcol][kp * 32 + q * 8];
                float4 v0 = *reinterpret_cast<const float4*>(p);
                float4 v1 = *reinterpret_cast<const float4*>(p + 4);
                split8(v0, v1, aH, aL);
            }
            #pragma unroll
            for (int no = 0; no < 4; ++no) {
                const size_t fo = ((size_t)(kp * 8 + wcol * 4 + no) * 64 + lane) * 8;
                short8 bh = *reinterpret_cast<const short8*>(Wc1Sw + fo);
                short8 bo = *reinterpret_cast<const short8*>(Wc1Sw + 16384 + fo);
                acc2[no] = __builtin_amdgcn_mfma_f32_16x16x32_bf16(aH, bh, acc2[no], 0, 0, 0);
                acc2[no] = __builtin_amdgcn_mfma_f32_16x16x32_bf16(aL, bh, acc2[no], 0, 0, 0);
                acc2[no] = __builtin_amdgcn_mfma_f32_16x16x32_bf16(aH, bo, acc2[no], 0, 0, 0);
            }
        }
        #pragma unroll
        for (int no = 0; no < 4; ++no) {
            const int col = wcol * 64 + no * 16 + mcol;
            const float bias = bc1[col];
            #pragma unroll
            for (int ri = 0; ri < 4; ++ri) {
                const int lrow = wrow * 16 + q * 4 + ri;
                Hs[lrow][col] = fmaxf(acc2[no][ri] + bias, 0.0f);
            }
        }
    }
    __syncthreads();

    // ---- stage 3
    {
        f32x4 acc3 = (f32x4){0.f, 0.f, 0.f, 0.f};
        #pragma unroll
        for (int kp = 0; kp < 4; ++kp) {
            short8 aH, aL;
            {
                const float* p = &Hs[wrow * 16 + mcol][kp * 32 + q * 8];
                float4 v0 = *reinterpret_cast<const float4*>(p);
                float4 v1 = *reinterpret_cast<const float4*>(p + 4);
                split8(v0, v1, aH, aL);
            }
            const size_t fo = ((size_t)(kp * 2 + wcol) * 64 + lane) * 8;
            short8 bh = *reinterpret_cast<const short8*>(Wc2Sw + fo);
            short8 bo = *reinterpret_cast<const short8*>(Wc2Sw + 4096 + fo);
            acc3 = __builtin_amdgcn_mfma_f32_16x16x32_bf16(aH, bh, acc3, 0, 0, 0);
            acc3 = __builtin_amdgcn_mfma_f32_16x16x32_bf16(aL, bh, acc3, 0, 0, 0);
            acc3 = __builtin_amdgcn_mfma_f32_16x16x32_bf16(aH, bo, acc3, 0, 0, 0);
        }
        const int col = wcol * 16 + mcol;
        const float b2 = bc2[col];
        #pragma unroll
        for (int ri = 0; ri < 4; ++ri) {
            const int row = rb + wrow * 16 + q * 4 + ri;
            if (row < nrows) out[(size_t)row * C + col] = acc3[ri] + b2;
        }
    }
}

// ---------------- launch ----------------

extern "C" void kernel_launch(void* const* d_in, const int* in_sizes, int n_in,
                              void* d_out, int out_size, void* d_ws, size_t ws_size,
                              hipStream_t stream) {
    const float* node_state = (const float*)d_in[0];
    const int*   edge_index = (const int*)d_in[1];
    const int*   label_pos  = (const int*)d_in[2];
    const float* W1l = (const float*)d_in[3];
    const float* b1l = (const float*)d_in[4];
    const float* W1r = (const float*)d_in[5];
    const float* W2l = (const float*)d_in[6];
    const float* b2l = (const float*)d_in[7];
    const float* W2r = (const float*)d_in[8];
    const float* Wc1 = (const float*)d_in[9];
    const float* bc1 = (const float*)d_in[10];
    const float* Wc2 = (const float*)d_in[11];
    const float* bc2 = (const float*)d_in[12];
    float* out = (float*)d_out;

    const int* src = edge_index;       // edge_index[0]
    const int* dst = edge_index + E;   // edge_index[1]

    // workspace layout (floats first for alignment)
    char* ws = (char*)d_ws;
    float* x1c   = (float*)ws;                    ws += sizeof(float) * (size_t)N * D;
    float* bufA  = (float*)ws;                    ws += sizeof(float) * (size_t)N * D;
    unsigned short* Wsw = (unsigned short*)ws;    ws += sizeof(unsigned short) * (5 * 32768 + 8192);
    int* deg     = (int*)ws;                      ws += sizeof(int) * N;   // |
    int* flag    = (int*)ws;                      ws += sizeof(int) * N;   // | contiguous: one
    int* labflag = (int*)ws;                      ws += sizeof(int) * N;   // | memset covers
    int* ucnt    = (int*)ws;                      ws += sizeof(int);       // | deg..sync4
    int* sync4   = (int*)ws;                      ws += sizeof(int) * 4;   // |
    float* sink  = (float*)ws;                    ws += sizeof(float);
    ws += sizeof(int) * 2;                        // pad
    int* roff    = (int*)ws;                      ws += sizeof(int) * (N + 1);
    int* cur     = (int*)ws;                      ws += sizeof(int) * N;
    int* csr_src = (int*)ws;                      ws += sizeof(int) * E;
    int* map     = (int*)ws;                      ws += sizeof(int) * N;
    int* ulist   = (int*)ws;                      ws += sizeof(int) * N;
    int* bsum    = (int*)ws;                      ws += sizeof(int) * 256;
    // bufA: mean1c [ucnt][D]; then mean2g [B][D]
    float* mean1c = bufA;
    float* mean2g = bufA;

    const int TB = 256;
    const int EB = (E + TB - 1) / TB;   // 2344 edge blocks

    // ---- preprocessing: 3 dispatches + 1 memset ----
    hipMemsetAsync(deg, 0, sizeof(int) * (3 * N + 5), stream);  // deg,flag,labflag,ucnt,sync4
    lab_k<<<(B + TB - 1) / TB, TB, 0, stream>>>(label_pos, labflag, flag, B);
    deg_swz_k<<<EB + 81 + TOUCHB, TB, 0, stream>>>(src, dst, labflag, deg, flag, E, EB,
                                                   W1l, W1r, W2l, W2r, Wc1, Wc2, Wsw,
                                                   node_state, sink);
    prep_k<<<2 * NB, 256, 0, stream>>>(deg, flag, src, dst, bsum, roff, cur,
                                       map, ulist, ucnt, csr_src, sync4, E, EB);

    // ---- layer 1: only U rows (compact outputs) ----
    gather_mean_k<true, false><<<(N + 3) / 4, TB, 0, stream>>>(
        node_state, roff, csr_src, ulist, nullptr, ucnt, mean1c, N);
    sage_mfma_k<true, false><<<(N + 31) / 32, TB, 0, stream>>>(
        mean1c, node_state, ulist, nullptr, ucnt,
        Wsw, Wsw + 32768, b1l, x1c, N);

    // ---- layer 2 + classifier (fused; label rows; all stages MFMA) ----
    gather_mean_k<true, true><<<(B + 3) / 4, TB, 0, stream>>>(
        x1c, roff, csr_src, label_pos, map, nullptr, mean2g, B);
    sage2_cls_k<<<(B + 31) / 32, TB, 0, stream>>>(
        mean2g, x1c, label_pos, map,
        Wsw + 65536, Wsw + 98304, b2l,
        Wsw + 131072, bc1,
        Wsw + 163840, bc2, out, B);
}

// Round 11
// 252.264 us; speedup vs baseline: 2.0679x; 1.0915x over previous
//
#include <hip/hip_runtime.h>
#include <hip/hip_bf16.h>

// Problem constants (match reference setup_inputs)
static constexpr int N = 100000;
static constexpr int E = 600000;
static constexpr int D = 128;
static constexpr int B = 10000;
static constexpr int C = 32;
static constexpr int NB = (N + 1023) / 1024;   // 98 scan chunks per N-array
static constexpr int TOUCHB = (N * (D / 4) + 255) / 256;   // 12500 float4-touch blocks

typedef __attribute__((ext_vector_type(8))) short short8;   // 8 bf16 (4 VGPRs)
typedef __attribute__((ext_vector_type(4))) float f32x4;    // MFMA acc

// bf16 RNE helpers (bit-level, no NaN inputs here)
static __device__ __forceinline__ unsigned short f2bf(float f) {
    unsigned u = __float_as_uint(f);
    unsigned r = (u + 0x7FFFu + ((u >> 16) & 1u)) >> 16;
    return (unsigned short)r;
}
static __device__ __forceinline__ float bf2f(unsigned short h) {
    return __uint_as_float(((unsigned)h) << 16);
}

// split 8 consecutive floats into hi/lo bf16 fragments
static __device__ __forceinline__ void split8(const float4 v0, const float4 v1,
                                              short8& h, short8& l) {
    const float f[8] = {v0.x, v0.y, v0.z, v0.w, v1.x, v1.y, v1.z, v1.w};
    #pragma unroll
    for (int i = 0; i < 8; ++i) {
        unsigned short hh = f2bf(f[i]);
        h[i] = (short)hh;
        l[i] = (short)f2bf(f[i] - bf2f(hh));
    }
}

// ---------------- label marking ----------------
__global__ void lab_k(const int* __restrict__ label_pos, int* __restrict__ labflag,
                      int* __restrict__ flag, int nlab) {
    int i = blockIdx.x * blockDim.x + threadIdx.x;
    if (i < nlab) {
        int v = label_pos[i];
        labflag[v] = 1;
        flag[v] = 1;   // labels are in U
    }
}

// ---------------- merged edge pass (deg + U-mark) + weight swizzle + L3 touch ----------------
// (verbatim R5 structure)
__global__ __launch_bounds__(256) void deg_swz_k(
    const int* __restrict__ src, const int* __restrict__ dst,
    const int* __restrict__ labflag,
    int* __restrict__ deg, int* __restrict__ flag, int nE, int EB,
    const float* W0, const float* W1, const float* W2, const float* W3,
    const float* W4, const float* W5,
    unsigned short* __restrict__ out,
    const float* __restrict__ xtouch, float* __restrict__ sink) {
    if ((int)blockIdx.x < EB) {
        int e = blockIdx.x * 256 + threadIdx.x;
        if (e < nE) {
            int d = dst[e];
            atomicAdd(&deg[d], 1);
            if (labflag[d]) flag[src[e]] = 1;   // benign race, all write 1
        }
        return;
    }
    if ((int)blockIdx.x < EB + 80) {
        const int sb = blockIdx.x - EB;          // 0..79
        const int m = sb >> 4;                   // 0..4
        const int chunk = sb & 15;
        const float* W = (m == 0) ? W0 : (m == 1) ? W1 : (m == 2) ? W2
                       : (m == 3) ? W3 : W4;
        unsigned short* o = out + (size_t)m * 32768;
        #pragma unroll
        for (int it = 0; it < 4; ++it) {
            int f = chunk * 1024 + it * 256 + threadIdx.x;   // 0..16383
            int j = f & 7;
            int lane = (f >> 3) & 63;
            int fi = f >> 9;                                 // ko*8+no
            int k = (fi >> 3) * 32 + (lane >> 4) * 8 + j;
            int n = (fi & 7) * 16 + (lane & 15);
            float a = W[k * 128 + n];
            unsigned short h = f2bf(a);
            o[f] = h;
            o[16384 + f] = f2bf(a - bf2f(h));
        }
        return;
    }
    if ((int)blockIdx.x == EB + 80) {
        unsigned short* o2 = out + (size_t)5 * 32768;
        #pragma unroll
        for (int it = 0; it < 16; ++it) {
            int f = it * 256 + threadIdx.x;   // 0..4095
            int j = f & 7;
            int lane = (f >> 3) & 63;
            int fi = f >> 9;                  // 0..7 = kp*2+no2
            int k = (fi >> 1) * 32 + (lane >> 4) * 8 + j;
            int n = (fi & 1) * 16 + (lane & 15);
            float a = W5[k * 32 + n];
            unsigned short h = f2bf(a);
            o2[f] = h;
            o2[4096 + f] = f2bf(a - bf2f(h));
        }
        return;
    }
    // ---- L3 warm touch of node_state
    const int f4 = (blockIdx.x - (EB + 81)) * 256 + threadIdx.x;
    if (f4 < N * (D / 4)) {
        float4 v = reinterpret_cast<const float4*>(xtouch)[f4];
        float s = v.x + v.y + v.z + v.w;
        if (s > 1e30f) *sink = s;   // data-dependent, never taken: keeps the loads
    }
}

// ---------------- fused scans ONLY (phases A+B of R10's prep_k; fill stays separate) ----------------
// 196 blocks <= 256 CUs => co-resident => software barrier safe (validated on HW in R10).
// Scans WANT 196 blocks; the R10 regression was fill-at-196-blocks, which is excluded here.
// Saves vs R5: one dispatch gap + scan3m's re-read of deg/flag + its redundant re-scan
// (chunk values and intra-block prefix stay in registers across the barrier).
__global__ __launch_bounds__(256) void prep12_k(
    const int* __restrict__ deg, const int* __restrict__ flag,
    int* __restrict__ bsum,
    int* __restrict__ roff, int* __restrict__ cur,
    int* __restrict__ map, int* __restrict__ ulist, int* __restrict__ ucnt,
    int* __restrict__ sync4)
{
    __shared__ int lsum[256];
    const int t = threadIdx.x;
    const bool isdeg = (int)blockIdx.x < NB;
    const int bloc = isdeg ? blockIdx.x : blockIdx.x - NB;
    const int gbase = isdeg ? 0 : NB;
    const int* v = isdeg ? deg : flag;

    // ---- phase A: chunk load + intra-block inclusive scan
    const int base = bloc * 1024 + t * 4;
    int dd[4];
    int s = 0;
    #pragma unroll
    for (int i = 0; i < 4; ++i) {
        int idx = base + i;
        dd[i] = (idx < N) ? v[idx] : 0;
        s += dd[i];
    }
    lsum[t] = s;
    __syncthreads();
    for (int off = 1; off < 256; off <<= 1) {
        int u = (t >= off) ? lsum[t - off] : 0;
        __syncthreads();
        lsum[t] += u;
        __syncthreads();
    }
    const int tpre = lsum[t] - s;           // exclusive prefix within block
    const int sblk = lsum[255];             // block total (all threads see it post-scan)
    if (t == 0) bsum[blockIdx.x] = sblk;
    __syncthreads();

    // ---- global barrier (validated machinery from R10)
    __threadfence();
    if (t == 0) {
        int old = atomicAdd(&sync4[0], 1);
        if (old == 2 * NB - 1) atomicExch(&sync4[1], 1);
        while (atomicAdd(&sync4[1], 0) == 0) {}
    }
    __syncthreads();

    // ---- self-service group prefix: boff = sum of bsum[gbase .. gbase+bloc-1]
    int pv = 0;
    if (t < bloc) pv = atomicAdd(&bsum[gbase + t], 0);   // coherent read
    lsum[t] = pv;
    __syncthreads();
    for (int off = 128; off > 0; off >>= 1) {
        if (t < off) lsum[t] += lsum[t + off];
        __syncthreads();
    }
    const int boffv = lsum[0];
    if (bloc == NB - 1 && t == 0) {
        if (isdeg) roff[N] = boffv + sblk;   // == E
        else *ucnt = boffv + sblk;
    }

    // ---- phase B: apply (registers dd/tpre survived the barrier)
    int run = boffv + tpre;
    #pragma unroll
    for (int i = 0; i < 4; ++i) {
        int idx = base + i;
        if (idx < N) {
            if (isdeg) {
                roff[idx] = run;
                cur[idx]  = run;
                run += dd[i];
            } else if (dd[i]) {
                map[idx] = run;
                ulist[run] = idx;
                ++run;
            }
        }
    }
}

// ---------------- CSR fill, full 2344-block parallelism (verbatim R5) ----------------
__global__ void fill_k(const int* __restrict__ src, const int* __restrict__ dst,
                       const int* __restrict__ flag,
                       int* __restrict__ cur, int* __restrict__ csr_src, int nE) {
    int e = blockIdx.x * blockDim.x + threadIdx.x;
    if (e < nE) {
        int d = dst[e];
        if (flag[d]) {
            int p = atomicAdd(&cur[d], 1);
            csr_src[p] = src[e];
        }
    }
}

// ---------------- gather-mean aggregation (verbatim R5) ----------------
template <bool GATHER, bool MAP>
__global__ __launch_bounds__(256) void gather_mean_k(
    const float* __restrict__ x, const int* __restrict__ roff,
    const int* __restrict__ csr_src, const int* __restrict__ rows,
    const int* __restrict__ map, const int* __restrict__ nrows_ptr,
    float* __restrict__ out, int nrows_max) {
    const int nrows = nrows_ptr ? nrows_ptr[0] : nrows_max;
    const int w = blockIdx.x * (blockDim.x >> 6) + (threadIdx.x >> 6);
    if (w >= nrows) return;
    const int lane = threadIdx.x & 63;
    const int n  = GATHER ? rows[w] : w;
    const int jb = roff[n];
    const int je = roff[n + 1];
    const float* xb = x + lane * 2;

    float ax = 0.f, ay = 0.f;
    int j = jb;
    for (; j + 4 <= je; j += 4) {
        int s0 = csr_src[j + 0];
        int s1 = csr_src[j + 1];
        int s2 = csr_src[j + 2];
        int s3 = csr_src[j + 3];
        if (MAP) { s0 = map[s0]; s1 = map[s1]; s2 = map[s2]; s3 = map[s3]; }
        float2 v0 = *reinterpret_cast<const float2*>(xb + (size_t)s0 * D);
        float2 v1 = *reinterpret_cast<const float2*>(xb + (size_t)s1 * D);
        float2 v2 = *reinterpret_cast<const float2*>(xb + (size_t)s2 * D);
        float2 v3 = *reinterpret_cast<const float2*>(xb + (size_t)s3 * D);
        ax += v0.x + v1.x + v2.x + v3.x;
        ay += v0.y + v1.y + v2.y + v3.y;
    }
    for (; j < je; ++j) {
        int s = csr_src[j];
        if (MAP) s = map[s];
        float2 v = *reinterpret_cast<const float2*>(xb + (size_t)s * D);
        ax += v.x;
        ay += v.y;
    }
    const float inv = 1.0f / fmaxf((float)(je - jb), 1.0f);
    *reinterpret_cast<float2*>(out + (size_t)w * D + lane * 2) =
        make_float2(ax * inv, ay * inv);
}

// ---------------- SAGE layer 1, split-bf16 MFMA (verbatim R5) ----------------
template <bool GATHER, bool MAP>
__global__ __launch_bounds__(256, 6) void sage_mfma_k(
    const float* __restrict__ mean, const float* __restrict__ xsrc,
    const int* __restrict__ rows, const int* __restrict__ map,
    const int* __restrict__ nrows_ptr,
    const unsigned short* __restrict__ WlSw, const unsigned short* __restrict__ WrSw,
    const float* __restrict__ bl, float* __restrict__ xout, int nrows_max)
{
    const int nrows = nrows_ptr ? nrows_ptr[0] : nrows_max;
    const int rb = blockIdx.x * 32;
    if (rb >= nrows) return;

    const int t = threadIdx.x;
    const int wrow = (t >> 6) & 1;
    const int wcol = t >> 7;
    const int lane = t & 63;
    const int mcol = lane & 15;
    const int q = lane >> 4;
    const int r = rb + wrow * 16 + mcol;

    f32x4 acc[4];
    #pragma unroll
    for (int no = 0; no < 4; ++no) acc[no] = (f32x4){0.f, 0.f, 0.f, 0.f};

    size_t gidx = 0;
    if (r < nrows) {
        int g = GATHER ? rows[r] : r;
        if (MAP) g = map[g];
        gidx = (size_t)g;
    }

    #pragma unroll
    for (int br = 0; br < 2; ++br) {
        const unsigned short* __restrict__ Wm = br ? WrSw : WlSw;
        #pragma unroll
        for (int kp = 0; kp < 4; ++kp) {
            short8 aH, aL;
            {
                float4 v0 = make_float4(0.f, 0.f, 0.f, 0.f);
                float4 v1 = make_float4(0.f, 0.f, 0.f, 0.f);
                if (r < nrows) {
                    const float* p = (br == 0)
                        ? mean + (size_t)r * D + kp * 32 + q * 8
                        : xsrc + gidx * D + kp * 32 + q * 8;
                    v0 = *reinterpret_cast<const float4*>(p);
                    v1 = *reinterpret_cast<const float4*>(p + 4);
                }
                split8(v0, v1, aH, aL);
            }
            #pragma unroll
            for (int no = 0; no < 4; ++no) {
                const size_t fo = ((size_t)(kp * 8 + wcol * 4 + no) * 64 + lane) * 8;
                short8 bh = *reinterpret_cast<const short8*>(Wm + fo);
                short8 bo = *reinterpret_cast<const short8*>(Wm + 16384 + fo);
                acc[no] = __builtin_amdgcn_mfma_f32_16x16x32_bf16(aH, bh, acc[no], 0, 0, 0);
                acc[no] = __builtin_amdgcn_mfma_f32_16x16x32_bf16(aL, bh, acc[no], 0, 0, 0);
                acc[no] = __builtin_amdgcn_mfma_f32_16x16x32_bf16(aH, bo, acc[no], 0, 0, 0);
            }
        }
    }

    #pragma unroll
    for (int no = 0; no < 4; ++no) {
        const int col = wcol * 64 + no * 16 + mcol;
        const float bias = bl[col];
        #pragma unroll
        for (int ri = 0; ri < 4; ++ri) {
            const int row = rb + wrow * 16 + q * 4 + ri;
            if (row < nrows)
                xout[(size_t)row * D + col] = fmaxf(acc[no][ri] + bias, 0.f);
        }
    }
}

// ---------------- fused layer-2 + classifier (verbatim R5) ----------------
__global__ __launch_bounds__(256) void sage2_cls_k(
    const float* __restrict__ mean, const float* __restrict__ x1c,
    const int* __restrict__ label_pos, const int* __restrict__ map,
    const unsigned short* __restrict__ WlSw, const unsigned short* __restrict__ WrSw,
    const float* __restrict__ bl,
    const unsigned short* __restrict__ Wc1Sw, const float* __restrict__ bc1,
    const unsigned short* __restrict__ Wc2Sw, const float* __restrict__ bc2,
    float* __restrict__ out, int nrows)
{
    __shared__ alignas(16) float Xs[32][132];   // x2 tile (+4 pad)
    __shared__ alignas(16) float Hs[32][132];   // h tile (+4 pad: conflict-free A-reads)
    const int rb = blockIdx.x * 32;
    const int t = threadIdx.x;
    const int wrow = (t >> 6) & 1;
    const int wcol = t >> 7;
    const int lane = t & 63;
    const int mcol = lane & 15;
    const int q = lane >> 4;
    const int r = rb + wrow * 16 + mcol;

    // ---- stage 1
    f32x4 acc[4];
    #pragma unroll
    for (int no = 0; no < 4; ++no) acc[no] = (f32x4){0.f, 0.f, 0.f, 0.f};

    size_t gidx = 0;
    if (r < nrows) gidx = (size_t)map[label_pos[r]];

    #pragma unroll
    for (int br = 0; br < 2; ++br) {
        const unsigned short* __restrict__ Wm = br ? WrSw : WlSw;
        #pragma unroll
        for (int kp = 0; kp < 4; ++kp) {
            short8 aH, aL;
            {
                float4 v0 = make_float4(0.f, 0.f, 0.f, 0.f);
                float4 v1 = make_float4(0.f, 0.f, 0.f, 0.f);
                if (r < nrows) {
                    const float* p = (br == 0)
                        ? mean + (size_t)r * D + kp * 32 + q * 8
                        : x1c + gidx * D + kp * 32 + q * 8;
                    v0 = *reinterpret_cast<const float4*>(p);
                    v1 = *reinterpret_cast<const float4*>(p + 4);
                }
                split8(v0, v1, aH, aL);
            }
            #pragma unroll
            for (int no = 0; no < 4; ++no) {
                const size_t fo = ((size_t)(kp * 8 + wcol * 4 + no) * 64 + lane) * 8;
                short8 bh = *reinterpret_cast<const short8*>(Wm + fo);
                short8 bo = *reinterpret_cast<const short8*>(Wm + 16384 + fo);
                acc[no] = __builtin_amdgcn_mfma_f32_16x16x32_bf16(aH, bh, acc[no], 0, 0, 0);
                acc[no] = __builtin_amdgcn_mfma_f32_16x16x32_bf16(aL, bh, acc[no], 0, 0, 0);
                acc[no] = __builtin_amdgcn_mfma_f32_16x16x32_bf16(aH, bo, acc[no], 0, 0, 0);
            }
        }
    }

    #pragma unroll
    for (int no = 0; no < 4; ++no) {
        const int col = wcol * 64 + no * 16 + mcol;
        const float bias = bl[col];
        #pragma unroll
        for (int ri = 0; ri < 4; ++ri) {
            const int lrow = wrow * 16 + q * 4 + ri;
            Xs[lrow][col] = fmaxf(acc[no][ri] + bias, 0.f);
        }
    }
    __syncthreads();

    // ---- stage 2
    {
        f32x4 acc2[4];
        #pragma unroll
        for (int no = 0; no < 4; ++no) acc2[no] = (f32x4){0.f, 0.f, 0.f, 0.f};

        #pragma unroll
        for (int kp = 0; kp < 4; ++kp) {
            short8 aH, aL;
            {
                const float* p = &Xs[wrow * 16 + mcol][kp * 32 + q * 8];
                float4 v0 = *reinterpret_cast<const float4*>(p);
                float4 v1 = *reinterpret_cast<const float4*>(p + 4);
                split8(v0, v1, aH, aL);
            }
            #pragma unroll
            for (int no = 0; no < 4; ++no) {
                const size_t fo = ((size_t)(kp * 8 + wcol * 4 + no) * 64 + lane) * 8;
                short8 bh = *reinterpret_cast<const short8*>(Wc1Sw + fo);
                short8 bo = *reinterpret_cast<const short8*>(Wc1Sw + 16384 + fo);
                acc2[no] = __builtin_amdgcn_mfma_f32_16x16x32_bf16(aH, bh, acc2[no], 0, 0, 0);
                acc2[no] = __builtin_amdgcn_mfma_f32_16x16x32_bf16(aL, bh, acc2[no], 0, 0, 0);
                acc2[no] = __builtin_amdgcn_mfma_f32_16x16x32_bf16(aH, bo, acc2[no], 0, 0, 0);
            }
        }
        #pragma unroll
        for (int no = 0; no < 4; ++no) {
            const int col = wcol * 64 + no * 16 + mcol;
            const float bias = bc1[col];
            #pragma unroll
            for (int ri = 0; ri < 4; ++ri) {
                const int lrow = wrow * 16 + q * 4 + ri;
                Hs[lrow][col] = fmaxf(acc2[no][ri] + bias, 0.0f);
            }
        }
    }
    __syncthreads();

    // ---- stage 3
    {
        f32x4 acc3 = (f32x4){0.f, 0.f, 0.f, 0.f};
        #pragma unroll
        for (int kp = 0; kp < 4; ++kp) {
            short8 aH, aL;
            {
                const float* p = &Hs[wrow * 16 + mcol][kp * 32 + q * 8];
                float4 v0 = *reinterpret_cast<const float4*>(p);
                float4 v1 = *reinterpret_cast<const float4*>(p + 4);
                split8(v0, v1, aH, aL);
            }
            const size_t fo = ((size_t)(kp * 2 + wcol) * 64 + lane) * 8;
            short8 bh = *reinterpret_cast<const short8*>(Wc2Sw + fo);
            short8 bo = *reinterpret_cast<const short8*>(Wc2Sw + 4096 + fo);
            acc3 = __builtin_amdgcn_mfma_f32_16x16x32_bf16(aH, bh, acc3, 0, 0, 0);
            acc3 = __builtin_amdgcn_mfma_f32_16x16x32_bf16(aL, bh, acc3, 0, 0, 0);
            acc3 = __builtin_amdgcn_mfma_f32_16x16x32_bf16(aH, bo, acc3, 0, 0, 0);
        }
        const int col = wcol * 16 + mcol;
        const float b2 = bc2[col];
        #pragma unroll
        for (int ri = 0; ri < 4; ++ri) {
            const int row = rb + wrow * 16 + q * 4 + ri;
            if (row < nrows) out[(size_t)row * C + col] = acc3[ri] + b2;
        }
    }
}

// ---------------- launch ----------------

extern "C" void kernel_launch(void* const* d_in, const int* in_sizes, int n_in,
                              void* d_out, int out_size, void* d_ws, size_t ws_size,
                              hipStream_t stream) {
    const float* node_state = (const float*)d_in[0];
    const int*   edge_index = (const int*)d_in[1];
    const int*   label_pos  = (const int*)d_in[2];
    const float* W1l = (const float*)d_in[3];
    const float* b1l = (const float*)d_in[4];
    const float* W1r = (const float*)d_in[5];
    const float* W2l = (const float*)d_in[6];
    const float* b2l = (const float*)d_in[7];
    const float* W2r = (const float*)d_in[8];
    const float* Wc1 = (const float*)d_in[9];
    const float* bc1 = (const float*)d_in[10];
    const float* Wc2 = (const float*)d_in[11];
    const float* bc2 = (const float*)d_in[12];
    float* out = (float*)d_out;

    const int* src = edge_index;       // edge_index[0]
    const int* dst = edge_index + E;   // edge_index[1]

    // workspace layout (floats first for alignment)
    char* ws = (char*)d_ws;
    float* x1c   = (float*)ws;                    ws += sizeof(float) * (size_t)N * D;
    float* bufA  = (float*)ws;                    ws += sizeof(float) * (size_t)N * D;
    unsigned short* Wsw = (unsigned short*)ws;    ws += sizeof(unsigned short) * (5 * 32768 + 8192);
    int* deg     = (int*)ws;                      ws += sizeof(int) * N;   // |
    int* flag    = (int*)ws;                      ws += sizeof(int) * N;   // | contiguous: one
    int* labflag = (int*)ws;                      ws += sizeof(int) * N;   // | memset covers
    int* ucnt    = (int*)ws;                      ws += sizeof(int);       // | deg..sync4
    int* sync4   = (int*)ws;                      ws += sizeof(int) * 4;   // |
    float* sink  = (float*)ws;                    ws += sizeof(float);
    ws += sizeof(int) * 2;                        // pad
    int* roff    = (int*)ws;                      ws += sizeof(int) * (N + 1);
    int* cur     = (int*)ws;                      ws += sizeof(int) * N;
    int* csr_src = (int*)ws;                      ws += sizeof(int) * E;
    int* map     = (int*)ws;                      ws += sizeof(int) * N;
    int* ulist   = (int*)ws;                      ws += sizeof(int) * N;
    int* bsum    = (int*)ws;                      ws += sizeof(int) * 256;
    // bufA: mean1c [ucnt][D]; then mean2g [B][D]
    float* mean1c = bufA;
    float* mean2g = bufA;

    const int TB = 256;
    const int EB = (E + TB - 1) / TB;   // 2344 edge blocks

    // ---- preprocessing: 4 dispatches + 1 memset ----
    hipMemsetAsync(deg, 0, sizeof(int) * (3 * N + 5), stream);  // deg,flag,labflag,ucnt,sync4
    lab_k<<<(B + TB - 1) / TB, TB, 0, stream>>>(label_pos, labflag, flag, B);
    deg_swz_k<<<EB + 81 + TOUCHB, TB, 0, stream>>>(src, dst, labflag, deg, flag, E, EB,
                                                   W1l, W1r, W2l, W2r, Wc1, Wc2, Wsw,
                                                   node_state, sink);
    prep12_k<<<2 * NB, 256, 0, stream>>>(deg, flag, bsum, roff, cur,
                                         map, ulist, ucnt, sync4);
    fill_k<<<EB, TB, 0, stream>>>(src, dst, flag, cur, csr_src, E);

    // ---- layer 1: only U rows (compact outputs) ----
    gather_mean_k<true, false><<<(N + 3) / 4, TB, 0, stream>>>(
        node_state, roff, csr_src, ulist, nullptr, ucnt, mean1c, N);
    sage_mfma_k<true, false><<<(N + 31) / 32, TB, 0, stream>>>(
        mean1c, node_state, ulist, nullptr, ucnt,
        Wsw, Wsw + 32768, b1l, x1c, N);

    // ---- layer 2 + classifier (fused; label rows; all stages MFMA) ----
    gather_mean_k<true, true><<<(B + 3) / 4, TB, 0, stream>>>(
        x1c, roff, csr_src, label_pos, map, nullptr, mean2g, B);
    sage2_cls_k<<<(B + 31) / 32, TB, 0, stream>>>(
        mean2g, x1c, label_pos, map,
        Wsw + 65536, Wsw + 98304, b2l,
        Wsw + 131072, bc1,
        Wsw + 163840, bc2, out, B);
}

// Round 14
// 239.569 us; speedup vs baseline: 2.1774x; 1.0530x over previous
//
#include <hip/hip_runtime.h>
#include <hip/hip_bf16.h>

// Problem constants (match reference setup_inputs)
static constexpr int N = 100000;
static constexpr int E = 600000;
static constexpr int D = 128;
static constexpr int B = 10000;
static constexpr int C = 32;
static constexpr int NB = (N + 1023) / 1024;   // 98 scan chunks per N-array
static constexpr int TOUCHB = (N * (D / 4) + 255) / 256;   // 12500 float4-touch blocks

typedef __attribute__((ext_vector_type(8))) short short8;   // 8 bf16 (4 VGPRs)
typedef __attribute__((ext_vector_type(4))) float f32x4;    // MFMA acc

// bf16 RNE helpers (bit-level, no NaN inputs here)
static __device__ __forceinline__ unsigned short f2bf(float f) {
    unsigned u = __float_as_uint(f);
    unsigned r = (u + 0x7FFFu + ((u >> 16) & 1u)) >> 16;
    return (unsigned short)r;
}
static __device__ __forceinline__ float bf2f(unsigned short h) {
    return __uint_as_float(((unsigned)h) << 16);
}

// split 8 consecutive floats into hi/lo bf16 fragments
static __device__ __forceinline__ void split8(const float4 v0, const float4 v1,
                                              short8& h, short8& l) {
    const float f[8] = {v0.x, v0.y, v0.z, v0.w, v1.x, v1.y, v1.z, v1.w};
    #pragma unroll
    for (int i = 0; i < 8; ++i) {
        unsigned short hh = f2bf(f[i]);
        h[i] = (short)hh;
        l[i] = (short)f2bf(f[i] - bf2f(hh));
    }
}

// ---------------- label marking ----------------
__global__ void lab_k(const int* __restrict__ label_pos, int* __restrict__ labflag,
                      int* __restrict__ flag, int nlab) {
    int i = blockIdx.x * blockDim.x + threadIdx.x;
    if (i < nlab) {
        int v = label_pos[i];
        labflag[v] = 1;
        flag[v] = 1;   // labels are in U
    }
}

// ---------------- merged edge pass (deg + U-mark) + weight swizzle + L3 touch ----------------
// (verbatim R5)
__global__ __launch_bounds__(256) void deg_swz_k(
    const int* __restrict__ src, const int* __restrict__ dst,
    const int* __restrict__ labflag,
    int* __restrict__ deg, int* __restrict__ flag, int nE, int EB,
    const float* W0, const float* W1, const float* W2, const float* W3,
    const float* W4, const float* W5,
    unsigned short* __restrict__ out,
    const float* __restrict__ xtouch, float* __restrict__ sink) {
    if ((int)blockIdx.x < EB) {
        int e = blockIdx.x * 256 + threadIdx.x;
        if (e < nE) {
            int d = dst[e];
            atomicAdd(&deg[d], 1);
            if (labflag[d]) flag[src[e]] = 1;   // benign race, all write 1
        }
        return;
    }
    if ((int)blockIdx.x < EB + 80) {
        const int sb = blockIdx.x - EB;          // 0..79
        const int m = sb >> 4;                   // 0..4
        const int chunk = sb & 15;
        const float* W = (m == 0) ? W0 : (m == 1) ? W1 : (m == 2) ? W2
                       : (m == 3) ? W3 : W4;
        unsigned short* o = out + (size_t)m * 32768;
        #pragma unroll
        for (int it = 0; it < 4; ++it) {
            int f = chunk * 1024 + it * 256 + threadIdx.x;   // 0..16383
            int j = f & 7;
            int lane = (f >> 3) & 63;
            int fi = f >> 9;                                 // ko*8+no
            int k = (fi >> 3) * 32 + (lane >> 4) * 8 + j;
            int n = (fi & 7) * 16 + (lane & 15);
            float a = W[k * 128 + n];
            unsigned short h = f2bf(a);
            o[f] = h;
            o[16384 + f] = f2bf(a - bf2f(h));
        }
        return;
    }
    if ((int)blockIdx.x == EB + 80) {
        // Wc2 swizzle: 128x32 -> 8 fragments per plane (4 k-chunks x 2 col tiles)
        unsigned short* o2 = out + (size_t)5 * 32768;
        #pragma unroll
        for (int it = 0; it < 16; ++it) {
            int f = it * 256 + threadIdx.x;   // 0..4095
            int j = f & 7;
            int lane = (f >> 3) & 63;
            int fi = f >> 9;                  // 0..7 = kp*2+no2
            int k = (fi >> 1) * 32 + (lane >> 4) * 8 + j;
            int n = (fi & 1) * 16 + (lane & 15);
            float a = W5[k * 32 + n];
            unsigned short h = f2bf(a);
            o2[f] = h;
            o2[4096 + f] = f2bf(a - bf2f(h));
        }
        return;
    }
    // ---- L3 warm touch of node_state
    const int f4 = (blockIdx.x - (EB + 81)) * 256 + threadIdx.x;
    if (f4 < N * (D / 4)) {
        float4 v = reinterpret_cast<const float4*>(xtouch)[f4];
        float s = v.x + v.y + v.z + v.w;
        if (s > 1e30f) *sink = s;   // data-dependent, never taken: keeps the loads
    }
}

// merged chunk sums with PER-ARRAY-ALIGNED chunking (verbatim R5)
__global__ __launch_bounds__(256) void scan1m_k(const int* __restrict__ deg,
                                                const int* __restrict__ flag,
                                                int* __restrict__ bsum, int n) {
    __shared__ int lsum[256];
    const int t = threadIdx.x;
    const bool isdeg = (int)blockIdx.x < NB;
    const int bloc = isdeg ? blockIdx.x : blockIdx.x - NB;
    const int* v = isdeg ? deg : flag;
    const int base = bloc * 1024 + t * 4;
    int s = 0;
    #pragma unroll
    for (int i = 0; i < 4; ++i) {
        int idx = base + i;
        if (idx < n) s += v[idx];
    }
    lsum[t] = s;
    __syncthreads();
    for (int off = 128; off > 0; off >>= 1) {
        if (t < off) lsum[t] += lsum[t + off];
        __syncthreads();
    }
    if (t == 0) bsum[blockIdx.x] = lsum[0];
}

// merged phase 3, fully independent groups (verbatim R5)
__global__ __launch_bounds__(256) void scan3m_k(
    const int* __restrict__ deg, const int* __restrict__ flag,
    const int* __restrict__ bsum,
    int* __restrict__ roff, int* __restrict__ cur,
    int* __restrict__ map, int* __restrict__ ulist, int* __restrict__ ucnt,
    int n)
{
    __shared__ int sb[128];
    __shared__ int lsum[256];
    const int t = threadIdx.x;
    const bool isdeg = (int)blockIdx.x < NB;
    const int bloc = isdeg ? blockIdx.x : blockIdx.x - NB;
    const int* bs = isdeg ? bsum : bsum + NB;
    const int* v  = isdeg ? deg : flag;

    if (t < 128) sb[t] = (t < NB) ? bs[t] : 0;
    __syncthreads();
    for (int off = 1; off < 128; off <<= 1) {
        int u = (t < 128 && t >= off) ? sb[t - off] : 0;
        __syncthreads();
        if (t < 128) sb[t] += u;
        __syncthreads();
    }
    const int boff = (bloc == 0) ? 0 : sb[bloc - 1];
    if (bloc == 0 && t == 0) {
        if (isdeg) roff[n] = sb[NB - 1];   // == E
        else *ucnt = sb[NB - 1];
    }

    const int base = bloc * 1024 + t * 4;
    int d[4];
    int s = 0;
    #pragma unroll
    for (int i = 0; i < 4; ++i) {
        int idx = base + i;
        d[i] = (idx < n) ? v[idx] : 0;
        s += d[i];
    }
    lsum[t] = s;
    __syncthreads();
    for (int off = 1; off < 256; off <<= 1) {
        int u = (t >= off) ? lsum[t - off] : 0;
        __syncthreads();
        lsum[t] += u;
        __syncthreads();
    }
    int run = boff + lsum[t] - s;
    #pragma unroll
    for (int i = 0; i < 4; ++i) {
        int idx = base + i;
        if (idx < n) {
            if (isdeg) {
                roff[idx] = run;
                cur[idx]  = run;
                run += d[i];
            } else if (d[i]) {
                map[idx] = run;
                ulist[run] = idx;
                ++run;
            }
        }
    }
}

// CSR fill restricted to dst in U (verbatim R5)
__global__ void fill_k(const int* __restrict__ src, const int* __restrict__ dst,
                       const int* __restrict__ flag,
                       int* __restrict__ cur, int* __restrict__ csr_src, int nE) {
    int e = blockIdx.x * blockDim.x + threadIdx.x;
    if (e < nE) {
        int d = dst[e];
        if (flag[d]) {
            int p = atomicAdd(&cur[d], 1);
            csr_src[p] = src[e];
        }
    }
}

// ---------------- gather-mean aggregation: 8-wide predicated batch ----------------
// ONLY change vs R5: 8 loads in flight per batch (out-of-range slots clamp to jb,
// masked out of the accumulate). Mean degree ~6 => deg<=8 rows (~84%) finish in ONE
// serialized latency chain instead of two.
template <bool GATHER, bool MAP>
__global__ __launch_bounds__(256) void gather_mean_k(
    const float* __restrict__ x, const int* __restrict__ roff,
    const int* __restrict__ csr_src, const int* __restrict__ rows,
    const int* __restrict__ map, const int* __restrict__ nrows_ptr,
    float* __restrict__ out, int nrows_max) {
    const int nrows = nrows_ptr ? nrows_ptr[0] : nrows_max;
    const int w = blockIdx.x * (blockDim.x >> 6) + (threadIdx.x >> 6);
    if (w >= nrows) return;
    const int lane = threadIdx.x & 63;
    const int n  = GATHER ? rows[w] : w;
    const int jb = roff[n];
    const int je = roff[n + 1];
    const float* xb = x + lane * 2;

    float ax = 0.f, ay = 0.f;
    for (int j = jb; j < je; j += 8) {
        float2 vv[8];
        #pragma unroll
        for (int u = 0; u < 8; ++u) {
            const int jj = j + u;
            int s = csr_src[(jj < je) ? jj : jb];
            if (MAP) s = map[s];
            vv[u] = *reinterpret_cast<const float2*>(xb + (size_t)s * D);
        }
        #pragma unroll
        for (int u = 0; u < 8; ++u) {
            if (j + u < je) { ax += vv[u].x; ay += vv[u].y; }
        }
    }
    const float inv = 1.0f / fmaxf((float)(je - jb), 1.0f);
    *reinterpret_cast<float2*>(out + (size_t)w * D + lane * 2) =
        make_float2(ax * inv, ay * inv);
}

// ---------------- SAGE layer 1, split-bf16 MFMA (verbatim R5) ----------------
template <bool GATHER, bool MAP>
__global__ __launch_bounds__(256, 6) void sage_mfma_k(
    const float* __restrict__ mean, const float* __restrict__ xsrc,
    const int* __restrict__ rows, const int* __restrict__ map,
    const int* __restrict__ nrows_ptr,
    const unsigned short* __restrict__ WlSw, const unsigned short* __restrict__ WrSw,
    const float* __restrict__ bl, float* __restrict__ xout, int nrows_max)
{
    const int nrows = nrows_ptr ? nrows_ptr[0] : nrows_max;
    const int rb = blockIdx.x * 32;
    if (rb >= nrows) return;

    const int t = threadIdx.x;
    const int wrow = (t >> 6) & 1;
    const int wcol = t >> 7;
    const int lane = t & 63;
    const int mcol = lane & 15;
    const int q = lane >> 4;
    const int r = rb + wrow * 16 + mcol;

    f32x4 acc[4];
    #pragma unroll
    for (int no = 0; no < 4; ++no) acc[no] = (f32x4){0.f, 0.f, 0.f, 0.f};

    size_t gidx = 0;
    if (r < nrows) {
        int g = GATHER ? rows[r] : r;
        if (MAP) g = map[g];
        gidx = (size_t)g;
    }

    #pragma unroll
    for (int br = 0; br < 2; ++br) {
        const unsigned short* __restrict__ Wm = br ? WrSw : WlSw;
        #pragma unroll
        for (int kp = 0; kp < 4; ++kp) {
            short8 aH, aL;
            {
                float4 v0 = make_float4(0.f, 0.f, 0.f, 0.f);
                float4 v1 = make_float4(0.f, 0.f, 0.f, 0.f);
                if (r < nrows) {
                    const float* p = (br == 0)
                        ? mean + (size_t)r * D + kp * 32 + q * 8
                        : xsrc + gidx * D + kp * 32 + q * 8;
                    v0 = *reinterpret_cast<const float4*>(p);
                    v1 = *reinterpret_cast<const float4*>(p + 4);
                }
                split8(v0, v1, aH, aL);
            }
            #pragma unroll
            for (int no = 0; no < 4; ++no) {
                const size_t fo = ((size_t)(kp * 8 + wcol * 4 + no) * 64 + lane) * 8;
                short8 bh = *reinterpret_cast<const short8*>(Wm + fo);
                short8 bo = *reinterpret_cast<const short8*>(Wm + 16384 + fo);
                acc[no] = __builtin_amdgcn_mfma_f32_16x16x32_bf16(aH, bh, acc[no], 0, 0, 0);
                acc[no] = __builtin_amdgcn_mfma_f32_16x16x32_bf16(aL, bh, acc[no], 0, 0, 0);
                acc[no] = __builtin_amdgcn_mfma_f32_16x16x32_bf16(aH, bo, acc[no], 0, 0, 0);
            }
        }
    }

    #pragma unroll
    for (int no = 0; no < 4; ++no) {
        const int col = wcol * 64 + no * 16 + mcol;
        const float bias = bl[col];
        #pragma unroll
        for (int ri = 0; ri < 4; ++ri) {
            const int row = rb + wrow * 16 + q * 4 + ri;
            if (row < nrows)
                xout[(size_t)row * D + col] = fmaxf(acc[no][ri] + bias, 0.f);
        }
    }
}

// ---------------- fused layer-2 + classifier (verbatim R5) ----------------
__global__ __launch_bounds__(256) void sage2_cls_k(
    const float* __restrict__ mean, const float* __restrict__ x1c,
    const int* __restrict__ label_pos, const int* __restrict__ map,
    const unsigned short* __restrict__ WlSw, const unsigned short* __restrict__ WrSw,
    const float* __restrict__ bl,
    const unsigned short* __restrict__ Wc1Sw, const float* __restrict__ bc1,
    const unsigned short* __restrict__ Wc2Sw, const float* __restrict__ bc2,
    float* __restrict__ out, int nrows)
{
    __shared__ alignas(16) float Xs[32][132];   // x2 tile (+4 pad)
    __shared__ alignas(16) float Hs[32][132];   // h tile (+4 pad: conflict-free A-reads)
    const int rb = blockIdx.x * 32;
    const int t = threadIdx.x;
    const int wrow = (t >> 6) & 1;
    const int wcol = t >> 7;
    const int lane = t & 63;
    const int mcol = lane & 15;
    const int q = lane >> 4;
    const int r = rb + wrow * 16 + mcol;

    // ---- stage 1
    f32x4 acc[4];
    #pragma unroll
    for (int no = 0; no < 4; ++no) acc[no] = (f32x4){0.f, 0.f, 0.f, 0.f};

    size_t gidx = 0;
    if (r < nrows) gidx = (size_t)map[label_pos[r]];

    #pragma unroll
    for (int br = 0; br < 2; ++br) {
        const unsigned short* __restrict__ Wm = br ? WrSw : WlSw;
        #pragma unroll
        for (int kp = 0; kp < 4; ++kp) {
            short8 aH, aL;
            {
                float4 v0 = make_float4(0.f, 0.f, 0.f, 0.f);
                float4 v1 = make_float4(0.f, 0.f, 0.f, 0.f);
                if (r < nrows) {
                    const float* p = (br == 0)
                        ? mean + (size_t)r * D + kp * 32 + q * 8
                        : x1c + gidx * D + kp * 32 + q * 8;
                    v0 = *reinterpret_cast<const float4*>(p);
                    v1 = *reinterpret_cast<const float4*>(p + 4);
                }
                split8(v0, v1, aH, aL);
            }
            #pragma unroll
            for (int no = 0; no < 4; ++no) {
                const size_t fo = ((size_t)(kp * 8 + wcol * 4 + no) * 64 + lane) * 8;
                short8 bh = *reinterpret_cast<const short8*>(Wm + fo);
                short8 bo = *reinterpret_cast<const short8*>(Wm + 16384 + fo);
                acc[no] = __builtin_amdgcn_mfma_f32_16x16x32_bf16(aH, bh, acc[no], 0, 0, 0);
                acc[no] = __builtin_amdgcn_mfma_f32_16x16x32_bf16(aL, bh, acc[no], 0, 0, 0);
                acc[no] = __builtin_amdgcn_mfma_f32_16x16x32_bf16(aH, bo, acc[no], 0, 0, 0);
            }
        }
    }

    // epilogue -> LDS tile (unconditional: junk rows masked at final store)
    #pragma unroll
    for (int no = 0; no < 4; ++no) {
        const int col = wcol * 64 + no * 16 + mcol;
        const float bias = bl[col];
        #pragma unroll
        for (int ri = 0; ri < 4; ++ri) {
            const int lrow = wrow * 16 + q * 4 + ri;
            Xs[lrow][col] = fmaxf(acc[no][ri] + bias, 0.f);
        }
    }
    __syncthreads();

    // ---- stage 2
    {
        f32x4 acc2[4];
        #pragma unroll
        for (int no = 0; no < 4; ++no) acc2[no] = (f32x4){0.f, 0.f, 0.f, 0.f};

        #pragma unroll
        for (int kp = 0; kp < 4; ++kp) {
            short8 aH, aL;
            {
                const float* p = &Xs[wrow * 16 + mcol][kp * 32 + q * 8];
                float4 v0 = *reinterpret_cast<const float4*>(p);
                float4 v1 = *reinterpret_cast<const float4*>(p + 4);
                split8(v0, v1, aH, aL);
            }
            #pragma unroll
            for (int no = 0; no < 4; ++no) {
                const size_t fo = ((size_t)(kp * 8 + wcol * 4 + no) * 64 + lane) * 8;
                short8 bh = *reinterpret_cast<const short8*>(Wc1Sw + fo);
                short8 bo = *reinterpret_cast<const short8*>(Wc1Sw + 16384 + fo);
                acc2[no] = __builtin_amdgcn_mfma_f32_16x16x32_bf16(aH, bh, acc2[no], 0, 0, 0);
                acc2[no] = __builtin_amdgcn_mfma_f32_16x16x32_bf16(aL, bh, acc2[no], 0, 0, 0);
                acc2[no] = __builtin_amdgcn_mfma_f32_16x16x32_bf16(aH, bo, acc2[no], 0, 0, 0);
            }
        }
        #pragma unroll
        for (int no = 0; no < 4; ++no) {
            const int col = wcol * 64 + no * 16 + mcol;
            const float bias = bc1[col];
            #pragma unroll
            for (int ri = 0; ri < 4; ++ri) {
                const int lrow = wrow * 16 + q * 4 + ri;
                Hs[lrow][col] = fmaxf(acc2[no][ri] + bias, 0.0f);
            }
        }
    }
    __syncthreads();

    // ---- stage 3
    {
        f32x4 acc3 = (f32x4){0.f, 0.f, 0.f, 0.f};
        #pragma unroll
        for (int kp = 0; kp < 4; ++kp) {
            short8 aH, aL;
            {
                const float* p = &Hs[wrow * 16 + mcol][kp * 32 + q * 8];
                float4 v0 = *reinterpret_cast<const float4*>(p);
                float4 v1 = *reinterpret_cast<const float4*>(p + 4);
                split8(v0, v1, aH, aL);
            }
            const size_t fo = ((size_t)(kp * 2 + wcol) * 64 + lane) * 8;
            short8 bh = *reinterpret_cast<const short8*>(Wc2Sw + fo);
            short8 bo = *reinterpret_cast<const short8*>(Wc2Sw + 4096 + fo);
            acc3 = __builtin_amdgcn_mfma_f32_16x16x32_bf16(aH, bh, acc3, 0, 0, 0);
            acc3 = __builtin_amdgcn_mfma_f32_16x16x32_bf16(aL, bh, acc3, 0, 0, 0);
            acc3 = __builtin_amdgcn_mfma_f32_16x16x32_bf16(aH, bo, acc3, 0, 0, 0);
        }
        const int col = wcol * 16 + mcol;
        const float b2 = bc2[col];
        #pragma unroll
        for (int ri = 0; ri < 4; ++ri) {
            const int row = rb + wrow * 16 + q * 4 + ri;
            if (row < nrows) out[(size_t)row * C + col] = acc3[ri] + b2;
        }
    }
}

// ---------------- launch ----------------

extern "C" void kernel_launch(void* const* d_in, const int* in_sizes, int n_in,
                              void* d_out, int out_size, void* d_ws, size_t ws_size,
                              hipStream_t stream) {
    const float* node_state = (const float*)d_in[0];
    const int*   edge_index = (const int*)d_in[1];
    const int*   label_pos  = (const int*)d_in[2];
    const float* W1l = (const float*)d_in[3];
    const float* b1l = (const float*)d_in[4];
    const float* W1r = (const float*)d_in[5];
    const float* W2l = (const float*)d_in[6];
    const float* b2l = (const float*)d_in[7];
    const float* W2r = (const float*)d_in[8];
    const float* Wc1 = (const float*)d_in[9];
    const float* bc1 = (const float*)d_in[10];
    const float* Wc2 = (const float*)d_in[11];
    const float* bc2 = (const float*)d_in[12];
    float* out = (float*)d_out;

    const int* src = edge_index;       // edge_index[0]
    const int* dst = edge_index + E;   // edge_index[1]

    // workspace layout (floats first for alignment)
    char* ws = (char*)d_ws;
    float* x1c   = (float*)ws;                    ws += sizeof(float) * (size_t)N * D;
    float* bufA  = (float*)ws;                    ws += sizeof(float) * (size_t)N * D;
    unsigned short* Wsw = (unsigned short*)ws;    ws += sizeof(unsigned short) * (5 * 32768 + 8192);
    int* deg     = (int*)ws;                      ws += sizeof(int) * N;   // |
    int* flag    = (int*)ws;                      ws += sizeof(int) * N;   // | contiguous: one
    int* labflag = (int*)ws;                      ws += sizeof(int) * N;   // | memset
    int* ucnt    = (int*)ws;                      ws += sizeof(int);       // |
    float* sink  = (float*)ws;                    ws += sizeof(float);
    ws += sizeof(int) * 2;                        // pad to 16B
    int* roff    = (int*)ws;                      ws += sizeof(int) * (N + 1);
    int* cur     = (int*)ws;                      ws += sizeof(int) * N;
    int* csr_src = (int*)ws;                      ws += sizeof(int) * E;
    int* map     = (int*)ws;                      ws += sizeof(int) * N;
    int* ulist   = (int*)ws;                      ws += sizeof(int) * N;
    int* bsum    = (int*)ws;                      ws += sizeof(int) * 256;
    // bufA: mean1c [ucnt][D]; then mean2g [B][D]
    float* mean1c = bufA;
    float* mean2g = bufA;

    const int TB = 256;
    const int EB = (E + TB - 1) / TB;   // 2344 edge blocks

    // ---- preprocessing: 5 dispatches + 1 memset (verbatim R5) ----
    hipMemsetAsync(deg, 0, sizeof(int) * (3 * N + 1), stream);  // deg,flag,labflag,ucnt
    lab_k<<<(B + TB - 1) / TB, TB, 0, stream>>>(label_pos, labflag, flag, B);
    deg_swz_k<<<EB + 81 + TOUCHB, TB, 0, stream>>>(src, dst, labflag, deg, flag, E, EB,
                                                   W1l, W1r, W2l, W2r, Wc1, Wc2, Wsw,
                                                   node_state, sink);
    scan1m_k<<<2 * NB, 256, 0, stream>>>(deg, flag, bsum, N);   // per-array-aligned chunks
    scan3m_k<<<2 * NB, 256, 0, stream>>>(deg, flag, bsum, roff, cur, map, ulist, ucnt, N);
    fill_k<<<EB, TB, 0, stream>>>(src, dst, flag, cur, csr_src, E);

    // ---- layer 1: only U rows (compact outputs) ----
    gather_mean_k<true, false><<<(N + 3) / 4, TB, 0, stream>>>(
        node_state, roff, csr_src, ulist, nullptr, ucnt, mean1c, N);
    sage_mfma_k<true, false><<<(N + 31) / 32, TB, 0, stream>>>(
        mean1c, node_state, ulist, nullptr, ucnt,
        Wsw, Wsw + 32768, b1l, x1c, N);

    // ---- layer 2 + classifier (fused; label rows; all stages MFMA) ----
    gather_mean_k<true, true><<<(B + 3) / 4, TB, 0, stream>>>(
        x1c, roff, csr_src, label_pos, map, nullptr, mean2g, B);
    sage2_cls_k<<<(B + 31) / 32, TB, 0, stream>>>(
        mean2g, x1c, label_pos, map,
        Wsw + 65536, Wsw + 98304, b2l,
        Wsw + 131072, bc1,
        Wsw + 163840, bc2, out, B);
}